// Round 1
// baseline (773.287 us; speedup 1.0000x reference)
//
#include <hip/hip_runtime.h>
#include <hip/hip_bf16.h>
#include <stdint.h>

#define HID 1024
#define FFD 4096
#define NE  8
#define NTOK 4096
#define BM 128
#define BN 128
#define BK 32
#define RBCAP 72
#define ROWCAP (RBCAP*BM)   // 9216

typedef __attribute__((ext_vector_type(8))) short short8;
typedef __attribute__((ext_vector_type(4))) float f32x4;

__device__ __forceinline__ unsigned short f2bf(float f){
  union { float f; unsigned u; } v; v.f = f;
  return (unsigned short)((v.u + 0x7FFFu + ((v.u >> 16) & 1u)) >> 16);  // RNE
}

__device__ __forceinline__ float gelu_f(float x){
  float u = 0.7978845608028654f * (x + 0.044715f * x * x * x);
  return 0.5f * x * (1.0f + tanhf(u));
}

__device__ __forceinline__ void gload_lds16(const void* g, void* l){
  __builtin_amdgcn_global_load_lds((const __attribute__((address_space(1))) void*)g,
                                   (__attribute__((address_space(3))) void*)l,
                                   16, 0, 0);
}

// ---------------- router: logits (f64 accum), softmax fp32, top-2 ----------------
__global__ __launch_bounds__(256) void router_k(
    const float* __restrict__ x, const float* __restrict__ Wr,
    float* __restrict__ out_logits, float* __restrict__ out_sel,
    int* __restrict__ counts, int* __restrict__ tok_sel, float* __restrict__ tok_w)
{
  const int lane = threadIdx.x & 63;
  const int t = (blockIdx.x << 2) + (threadIdx.x >> 6);
  const float* xr = x + (size_t)t * HID;
  double acc[NE];
  #pragma unroll
  for (int e = 0; e < NE; ++e) acc[e] = 0.0;
  #pragma unroll 4
  for (int h = lane; h < HID; h += 64) {
    float xv = xr[h];
    float4 w0 = *(const float4*)(Wr + (size_t)h * NE);
    float4 w1 = *(const float4*)(Wr + (size_t)h * NE + 4);
    acc[0] += (double)xv * w0.x;  acc[1] += (double)xv * w0.y;
    acc[2] += (double)xv * w0.z;  acc[3] += (double)xv * w0.w;
    acc[4] += (double)xv * w1.x;  acc[5] += (double)xv * w1.y;
    acc[6] += (double)xv * w1.z;  acc[7] += (double)xv * w1.w;
  }
  #pragma unroll
  for (int off = 32; off > 0; off >>= 1) {
    #pragma unroll
    for (int e = 0; e < NE; ++e) acc[e] += __shfl_down(acc[e], off);
  }
  if (lane == 0) {
    float lg[NE], p[NE];
    float mx = -3.4e38f;
    #pragma unroll
    for (int e = 0; e < NE; ++e) { lg[e] = (float)acc[e]; mx = fmaxf(mx, lg[e]); }
    float s = 0.f;
    #pragma unroll
    for (int e = 0; e < NE; ++e) { p[e] = expf(lg[e] - mx); s += p[e]; }
    float inv = 1.0f / s;
    #pragma unroll
    for (int e = 0; e < NE; ++e) p[e] *= inv;
    #pragma unroll
    for (int e = 0; e < NE; ++e) out_logits[(size_t)t * NE + e] = lg[e];
    int e0 = 0;
    #pragma unroll
    for (int e = 1; e < NE; ++e) if (p[e] > p[e0]) e0 = e;      // tie -> lower idx
    int e1 = (e0 == 0) ? 1 : 0;
    #pragma unroll
    for (int e = 0; e < NE; ++e) if (e != e0 && p[e] > p[e1]) e1 = e;
    out_sel[(size_t)t * 2 + 0] = (float)e0;
    out_sel[(size_t)t * 2 + 1] = (float)e1;
    tok_sel[t * 2 + 0] = e0;  tok_sel[t * 2 + 1] = e1;
    tok_w[t * 2 + 0] = p[e0]; tok_w[t * 2 + 1] = p[e1];
    atomicAdd(&counts[e0], 1); atomicAdd(&counts[e1], 1);
  }
}

// ---------------- scan: padded offsets + rowblock table ----------------
__global__ void scan_k(const int* __restrict__ counts, int* __restrict__ offs,
                       int* __restrict__ rb2e, int* __restrict__ rb2row, int* __restrict__ nrb)
{
  if (threadIdx.x == 0 && blockIdx.x == 0) {
    int row = 0, rb = 0;
    for (int e = 0; e < NE; ++e) {
      offs[e] = row;
      int n = counts[e];
      int nb = (n + BM - 1) / BM;
      for (int b = 0; b < nb; ++b) { rb2e[rb] = e; rb2row[rb] = row + b * BM; rb++; }
      row += nb * BM;
    }
    nrb[0] = rb;
  }
}

// ---------------- build pair lists ----------------
__global__ __launch_bounds__(256) void build_k(
    const int* __restrict__ tok_sel, const float* __restrict__ tok_w,
    const int* __restrict__ offs, int* __restrict__ cursors,
    int* __restrict__ pair_tok, float* __restrict__ pair_w)
{
  int t = blockIdx.x * 256 + threadIdx.x;
  #pragma unroll
  for (int j = 0; j < 2; ++j) {
    int e = tok_sel[t * 2 + j];
    int pos = atomicAdd(&cursors[e], 1);
    int p = offs[e] + pos;
    pair_tok[p] = t;
    pair_w[p] = tok_w[t * 2 + j];
  }
}

// ---------------- gather selected rows of x -> bf16 ----------------
__global__ __launch_bounds__(256) void gather_k(
    const float* __restrict__ x, const int* __restrict__ pair_tok, unsigned short* __restrict__ Xg)
{
  const int lane = threadIdx.x & 63;
  const int p = (blockIdx.x << 2) + (threadIdx.x >> 6);
  int t = pair_tok[p];
  if (t < 0) return;                       // padding row: never consumed
  const float* src = x + (size_t)t * HID;
  unsigned short* dst = Xg + (size_t)p * HID;
  #pragma unroll
  for (int i = 0; i < 4; ++i) {
    float4 v = *(const float4*)(src + lane * 4 + i * 256);
    unsigned a = (unsigned)f2bf(v.x) | ((unsigned)f2bf(v.y) << 16);
    unsigned b = (unsigned)f2bf(v.z) | ((unsigned)f2bf(v.w) << 16);
    *(uint2*)(dst + lane * 4 + i * 256) = make_uint2(a, b);
  }
}

// ---------------- expert-tiled GEMM (128x128 tile, bf16 MFMA) ----------------
// A: bf16 [rows][LDA] in ws.  W: fp32 [NE][KDIM][NDIM].  bias: fp32 [NE][NDIM].
// DOGELU: C = gelu(A@W + b) -> bf16 Hout.  else: out[tok] += w * (A@W + b) (atomic).
template<int KDIM, int NDIM, int LDA, bool DOGELU>
__global__ __launch_bounds__(256) void gemm_k(
    const unsigned short* __restrict__ A, const float* __restrict__ W,
    const float* __restrict__ bias,
    const int* __restrict__ nrb, const int* __restrict__ rb2e, const int* __restrict__ rb2row,
    unsigned short* __restrict__ Hout,
    const int* __restrict__ pair_tok, const float* __restrict__ pair_w,
    float* __restrict__ out)
{
  if ((int)blockIdx.y >= nrb[0]) return;
  const int e    = rb2e[blockIdx.y];
  const int row0 = rb2row[blockIdx.y];
  const int bn   = blockIdx.x * BN;

  __shared__ __align__(16) unsigned short As[BM * BK];   // [row][k] linear
  __shared__ __align__(16) unsigned short Bs[BN * BK];   // [n][k]  (transposed in LDS)

  const int tid = threadIdx.x;
  const int lane = tid & 63, wave = tid >> 6;
  const int wm = wave >> 1, wn = wave & 1;
  const float* Be = W + (size_t)e * KDIM * NDIM;

  f32x4 acc[4][4];
  #pragma unroll
  for (int m = 0; m < 4; ++m)
    #pragma unroll
    for (int n = 0; n < 4; ++n) acc[m][n] = f32x4{0.f, 0.f, 0.f, 0.f};

  const int bcol = tid & 127;           // B staging: column within tile
  const int k0   = (tid >> 7) * 16;     // B staging: k half

  for (int kt = 0; kt < KDIM; kt += BK) {
    // ---- A tile: 128x32 bf16 via async global->LDS (2 rounds of 256 lanes x 16B)
    #pragma unroll
    for (int r = 0; r < 2; ++r) {
      int c = r * 256 + tid;                      // 16B chunk id, 4 chunks/row
      int arow = c >> 2;
      int koff = (c & 3) * 8;
      const void* gp = (const void*)(A + (size_t)(row0 + arow) * LDA + kt + koff);
      void* lp = (void*)(As + (size_t)(r * 256 + wave * 64) * 8); // wave-uniform base
      gload_lds16(gp, lp);
    }
    // ---- B tile: 32x128 fp32 -> bf16, stored [n][k]; per thread one column, 16 k's
    const float* bp = Be + (size_t)(kt + k0) * NDIM + bn + bcol;
    float bv[16];
    #pragma unroll
    for (int k = 0; k < 16; ++k) bv[k] = bp[(size_t)k * NDIM];
    unsigned pk[8];
    #pragma unroll
    for (int k = 0; k < 8; ++k)
      pk[k] = (unsigned)f2bf(bv[2 * k]) | ((unsigned)f2bf(bv[2 * k + 1]) << 16);
    uint4* bd = (uint4*)&Bs[bcol * BK + k0];
    bd[0] = make_uint4(pk[0], pk[1], pk[2], pk[3]);
    bd[1] = make_uint4(pk[4], pk[5], pk[6], pk[7]);

    __syncthreads();

    const int kc = lane >> 4, rsel = lane & 15;
    short8 af[4], bf[4];
    #pragma unroll
    for (int m = 0; m < 4; ++m)
      af[m] = *(const short8*)&As[(wm * 64 + m * 16 + rsel) * BK + kc * 8];
    #pragma unroll
    for (int n = 0; n < 4; ++n)
      bf[n] = *(const short8*)&Bs[(wn * 64 + n * 16 + rsel) * BK + kc * 8];
    #pragma unroll
    for (int m = 0; m < 4; ++m)
      #pragma unroll
      for (int n = 0; n < 4; ++n)
        acc[m][n] = __builtin_amdgcn_mfma_f32_16x16x32_bf16(af[m], bf[n], acc[m][n], 0, 0, 0);

    __syncthreads();
  }

  // ---- epilogue.  C/D map: col = lane&15, row = (lane>>4)*4 + i   [m89/m91]
  const int rsel = lane & 15, quad = lane >> 4;
  float bvv[4];
  #pragma unroll
  for (int n = 0; n < 4; ++n)
    bvv[n] = bias[(size_t)e * NDIM + bn + wn * 64 + n * 16 + rsel];

  if constexpr (DOGELU) {
    #pragma unroll
    for (int m = 0; m < 4; ++m) {
      int r0 = row0 + wm * 64 + m * 16 + quad * 4;
      #pragma unroll
      for (int n = 0; n < 4; ++n) {
        int col = bn + wn * 64 + n * 16 + rsel;
        unsigned short* hp = Hout + (size_t)r0 * NDIM + col;
        #pragma unroll
        for (int i = 0; i < 4; ++i) {
          float v = acc[m][n][i] + bvv[n];
          hp[(size_t)i * NDIM] = f2bf(gelu_f(v));
        }
      }
    }
  } else {
    #pragma unroll
    for (int m = 0; m < 4; ++m) {
      #pragma unroll
      for (int i = 0; i < 4; ++i) {
        int p = row0 + wm * 64 + m * 16 + quad * 4 + i;
        int t = pair_tok[p];
        if (t < 0) continue;                    // padding row
        float w = pair_w[p];
        float* op = out + (size_t)t * HID;
        #pragma unroll
        for (int n = 0; n < 4; ++n) {
          int col = bn + wn * 64 + n * 16 + rsel;
          atomicAdd(op + col, w * (acc[m][n][i] + bvv[n]));
        }
      }
    }
  }
}

// ---------------- launch ----------------
extern "C" void kernel_launch(void* const* d_in, const int* in_sizes, int n_in,
                              void* d_out, int out_size, void* d_ws, size_t ws_size,
                              hipStream_t stream)
{
  const float* x  = (const float*)d_in[0];
  const float* Wr = (const float*)d_in[1];
  const float* W1 = (const float*)d_in[2];
  const float* b1 = (const float*)d_in[3];
  const float* W2 = (const float*)d_in[4];
  const float* b2 = (const float*)d_in[5];

  float* out        = (float*)d_out;                 // 4096*1024
  float* out_logits = out + (size_t)NTOK * HID;      // 4096*8
  float* out_sel    = out_logits + (size_t)NTOK * NE;// 4096*2 (as floats)

  char* ws = (char*)d_ws;
  int*   counts   = (int*)(ws + 0);        // 8
  int*   cursors  = (int*)(ws + 64);       // 8
  int*   nrb      = (int*)(ws + 128);      // 1
  int*   offs     = (int*)(ws + 192);      // 8
  int*   rb2e     = (int*)(ws + 256);      // 128
  int*   rb2row   = (int*)(ws + 768);      // 128
  int*   tok_sel  = (int*)(ws + 1280);     // 4096*2
  float* tok_w    = (float*)(ws + 34048);  // 4096*2
  int*   pair_tok = (int*)(ws + 66816);    // 9216
  float* pair_w   = (float*)(ws + 103680); // 9216
  unsigned short* Xg = (unsigned short*)(ws + 140800);    // 9216*1024 bf16
  unsigned short* H  = (unsigned short*)(ws + 19015168);  // 9216*4096 bf16

  hipMemsetAsync(ws, 0, 256, stream);                          // counts/cursors/nrb
  hipMemsetAsync(pair_tok, 0xFF, (size_t)ROWCAP * 4, stream);  // -1 = padding
  hipMemsetAsync(d_out, 0, (size_t)out_size * 4, stream);

  router_k<<<NTOK / 4, 256, 0, stream>>>(x, Wr, out_logits, out_sel, counts, tok_sel, tok_w);
  scan_k<<<1, 64, 0, stream>>>(counts, offs, rb2e, rb2row, nrb);
  build_k<<<NTOK / 256, 256, 0, stream>>>(tok_sel, tok_w, offs, cursors, pair_tok, pair_w);
  gather_k<<<ROWCAP / 4, 256, 0, stream>>>(x, pair_tok, Xg);

  dim3 g1(FFD / BN, RBCAP);
  gemm_k<HID, FFD, HID, true><<<g1, 256, 0, stream>>>(
      Xg, W1, b1, nrb, rb2e, rb2row, H, nullptr, nullptr, nullptr);
  dim3 g2(HID / BN, RBCAP);
  gemm_k<FFD, HID, FFD, false><<<g2, 256, 0, stream>>>(
      H, W2, b2, nrb, rb2e, rb2row, nullptr, pair_tok, pair_w, out);
}

// Round 4
// 767.638 us; speedup vs baseline: 1.0074x; 1.0074x over previous
//
#include <hip/hip_runtime.h>
#include <hip/hip_bf16.h>
#include <stdint.h>

#define HID 1024
#define FFD 4096
#define FFH 2048          // FF half
#define NE  8
#define NTOK 4096
#define BM 128
#define BN 128
#define BK 32
#define RBCAP 72
#define ROWCAP (RBCAP*BM)   // 9216

typedef __attribute__((ext_vector_type(8))) short short8;
typedef __attribute__((ext_vector_type(4))) float f32x4;

__device__ __forceinline__ unsigned short f2bf(float f){
  union { float f; unsigned u; } v; v.f = f;
  return (unsigned short)((v.u + 0x7FFFu + ((v.u >> 16) & 1u)) >> 16);  // RNE
}

__device__ __forceinline__ float gelu_f(float x){
  float u = 0.7978845608028654f * (x + 0.044715f * x * x * x);
  return 0.5f * x * (1.0f + tanhf(u));
}

__device__ __forceinline__ void gload_lds16(const void* g, void* l){
  __builtin_amdgcn_global_load_lds((const __attribute__((address_space(1))) void*)g,
                                   (__attribute__((address_space(3))) void*)l,
                                   16, 0, 0);
}

// ---------------- router: logits (f64 accum), softmax fp32, top-2 ----------------
__global__ __launch_bounds__(256) void router_k(
    const float* __restrict__ x, const float* __restrict__ Wr,
    float* __restrict__ out_logits, float* __restrict__ out_sel,
    int* __restrict__ counts, int* __restrict__ tok_sel, float* __restrict__ tok_w)
{
  const int lane = threadIdx.x & 63;
  const int t = (blockIdx.x << 2) + (threadIdx.x >> 6);
  const float* xr = x + (size_t)t * HID;
  double acc[NE];
  #pragma unroll
  for (int e = 0; e < NE; ++e) acc[e] = 0.0;
  #pragma unroll 4
  for (int h = lane; h < HID; h += 64) {
    float xv = xr[h];
    float4 w0 = *(const float4*)(Wr + (size_t)h * NE);
    float4 w1 = *(const float4*)(Wr + (size_t)h * NE + 4);
    acc[0] += (double)xv * w0.x;  acc[1] += (double)xv * w0.y;
    acc[2] += (double)xv * w0.z;  acc[3] += (double)xv * w0.w;
    acc[4] += (double)xv * w1.x;  acc[5] += (double)xv * w1.y;
    acc[6] += (double)xv * w1.z;  acc[7] += (double)xv * w1.w;
  }
  #pragma unroll
  for (int off = 32; off > 0; off >>= 1) {
    #pragma unroll
    for (int e = 0; e < NE; ++e) acc[e] += __shfl_down(acc[e], off);
  }
  if (lane == 0) {
    float lg[NE], p[NE];
    float mx = -3.4e38f;
    #pragma unroll
    for (int e = 0; e < NE; ++e) { lg[e] = (float)acc[e]; mx = fmaxf(mx, lg[e]); }
    float s = 0.f;
    #pragma unroll
    for (int e = 0; e < NE; ++e) { p[e] = expf(lg[e] - mx); s += p[e]; }
    float inv = 1.0f / s;
    #pragma unroll
    for (int e = 0; e < NE; ++e) p[e] *= inv;
    #pragma unroll
    for (int e = 0; e < NE; ++e) out_logits[(size_t)t * NE + e] = lg[e];
    int e0 = 0;
    #pragma unroll
    for (int e = 1; e < NE; ++e) if (p[e] > p[e0]) e0 = e;      // tie -> lower idx
    int e1 = (e0 == 0) ? 1 : 0;
    #pragma unroll
    for (int e = 0; e < NE; ++e) if (e != e0 && p[e] > p[e1]) e1 = e;
    out_sel[(size_t)t * 2 + 0] = (float)e0;
    out_sel[(size_t)t * 2 + 1] = (float)e1;
    tok_sel[t * 2 + 0] = e0;  tok_sel[t * 2 + 1] = e1;
    tok_w[t * 2 + 0] = p[e0]; tok_w[t * 2 + 1] = p[e1];
    atomicAdd(&counts[e0], 1); atomicAdd(&counts[e1], 1);
  }
}

// ---------------- scan: padded offsets + rowblock table ----------------
__global__ void scan_k(const int* __restrict__ counts, int* __restrict__ offs,
                       int* __restrict__ rb2e, int* __restrict__ rb2row, int* __restrict__ nrb)
{
  if (threadIdx.x == 0 && blockIdx.x == 0) {
    int row = 0, rb = 0;
    for (int e = 0; e < NE; ++e) {
      offs[e] = row;
      int n = counts[e];
      int nb = (n + BM - 1) / BM;
      for (int b = 0; b < nb; ++b) { rb2e[rb] = e; rb2row[rb] = row + b * BM; rb++; }
      row += nb * BM;
    }
    nrb[0] = rb;
  }
}

// ---------------- build pair lists ----------------
__global__ __launch_bounds__(256) void build_k(
    const int* __restrict__ tok_sel, const float* __restrict__ tok_w,
    const int* __restrict__ offs, int* __restrict__ cursors,
    int* __restrict__ pair_tok, float* __restrict__ pair_w)
{
  int t = blockIdx.x * 256 + threadIdx.x;
  #pragma unroll
  for (int j = 0; j < 2; ++j) {
    int e = tok_sel[t * 2 + j];
    int pos = atomicAdd(&cursors[e], 1);
    int p = offs[e] + pos;
    pair_tok[p] = t;
    pair_w[p] = tok_w[t * 2 + j];
  }
}

// ---------------- gather selected rows of x -> bf16 ----------------
__global__ __launch_bounds__(256) void gather_k(
    const float* __restrict__ x, const int* __restrict__ pair_tok, unsigned short* __restrict__ Xg)
{
  const int lane = threadIdx.x & 63;
  const int p = (blockIdx.x << 2) + (threadIdx.x >> 6);
  int t = pair_tok[p];
  if (t < 0) return;                       // padding row: never consumed
  const float* src = x + (size_t)t * HID;
  unsigned short* dst = Xg + (size_t)p * HID;
  #pragma unroll
  for (int i = 0; i < 4; ++i) {
    float4 v = *(const float4*)(src + lane * 4 + i * 256);
    unsigned a = (unsigned)f2bf(v.x) | ((unsigned)f2bf(v.y) << 16);
    unsigned b = (unsigned)f2bf(v.z) | ((unsigned)f2bf(v.w) << 16);
    *(uint2*)(dst + lane * 4 + i * 256) = make_uint2(a, b);
  }
}

// ------- generic weight transpose+convert: out[e][n][k] = bf16(in_e[k*ld_in + n]) -------
// in pre-offset to the desired (row,col) window; KSUB x NSUB window, per-expert strides given.
template<int KSUB, int NSUB>
__global__ __launch_bounds__(256) void wtrans_k(const float* __restrict__ in,
                                               unsigned short* __restrict__ out,
                                               int ld_in, size_t in_estride)
{
  const int tilesN = NSUB / 64;
  const int tk = blockIdx.x / tilesN, tn = blockIdx.x % tilesN;
  const int k0 = tk * 64, n0 = tn * 64;
  const float* ine = in + (size_t)blockIdx.y * in_estride;
  unsigned short* oute = out + (size_t)blockIdx.y * KSUB * NSUB;
  __shared__ unsigned short lds[64][65];   // [n][k]
  const int t = threadIdx.x;
  #pragma unroll
  for (int i = 0; i < 4; ++i) {
    int f = i * 256 + t;
    int krow = f >> 4, c4 = (f & 15) * 4;
    float4 v = *(const float4*)(ine + (size_t)(k0 + krow) * ld_in + n0 + c4);
    lds[c4 + 0][krow] = f2bf(v.x);
    lds[c4 + 1][krow] = f2bf(v.y);
    lds[c4 + 2][krow] = f2bf(v.z);
    lds[c4 + 3][krow] = f2bf(v.w);
  }
  __syncthreads();
  #pragma unroll
  for (int i = 0; i < 4; ++i) {
    int g = i * 256 + t;
    int nrow = g >> 4, kc = (g & 15) * 4;
    unsigned short a0 = lds[nrow][kc], a1 = lds[nrow][kc + 1];
    unsigned short a2 = lds[nrow][kc + 2], a3 = lds[nrow][kc + 3];
    uint2 w;
    w.x = (unsigned)a0 | ((unsigned)a1 << 16);
    w.y = (unsigned)a2 | ((unsigned)a3 << 16);
    *(uint2*)(oute + (size_t)(n0 + nrow) * KSUB + k0 + kc) = w;
  }
}

// ---------------- expert-tiled GEMM (m97 structure: both operands via global_load_lds) ----
// A: bf16 [rows][KDIM].  Bt: bf16 [NE][NDIM][KDIM] (k-contiguous).  bias fp32 (pre-offset).
template<int KDIM, int NDIM, int BIAS_STRIDE, bool DOGELU, bool ADD_BIAS>
__global__ __launch_bounds__(256) void gemm_k(
    const unsigned short* __restrict__ A, const unsigned short* __restrict__ Bt,
    const float* __restrict__ bias,
    const int* __restrict__ nrb, const int* __restrict__ rb2e, const int* __restrict__ rb2row,
    unsigned short* __restrict__ Hout,
    const int* __restrict__ pair_tok, const float* __restrict__ pair_w,
    float* __restrict__ out)
{
  if ((int)blockIdx.y >= nrb[0]) return;
  const int e    = rb2e[blockIdx.y];
  const int row0 = rb2row[blockIdx.y];
  const int bn   = blockIdx.x * BN;

  __shared__ __align__(16) unsigned short As[BM * BK];   // [row][k]
  __shared__ __align__(16) unsigned short Bs[BN * BK];   // [n][k]

  const int tid = threadIdx.x;
  const int lane = tid & 63, wave = tid >> 6;
  const int wm = wave >> 1, wn = wave & 1;
  const unsigned short* Be = Bt + (size_t)e * KDIM * NDIM;

  f32x4 acc[4][4];
  #pragma unroll
  for (int m = 0; m < 4; ++m)
    #pragma unroll
    for (int n = 0; n < 4; ++n) acc[m][n] = f32x4{0.f, 0.f, 0.f, 0.f};

  for (int kt = 0; kt < KDIM; kt += BK) {
    #pragma unroll
    for (int r = 0; r < 2; ++r) {
      int c = r * 256 + tid;
      int mrow = c >> 2;               // 4 chunks (=32 bf16) per row
      int koff = (c & 3) * 8;
      const void* gpa = (const void*)(A + (size_t)(row0 + mrow) * KDIM + kt + koff);
      void* lpa = (void*)(As + (size_t)(r * 256 + wave * 64) * 8);
      gload_lds16(gpa, lpa);
      const void* gpb = (const void*)(Be + (size_t)(bn + mrow) * KDIM + kt + koff);
      void* lpb = (void*)(Bs + (size_t)(r * 256 + wave * 64) * 8);
      gload_lds16(gpb, lpb);
    }
    __syncthreads();

    const int kc = lane >> 4, rsel0 = lane & 15;
    short8 af[4], bfr[4];
    #pragma unroll
    for (int m = 0; m < 4; ++m)
      af[m] = *(const short8*)&As[(wm * 64 + m * 16 + rsel0) * BK + kc * 8];
    #pragma unroll
    for (int n = 0; n < 4; ++n)
      bfr[n] = *(const short8*)&Bs[(wn * 64 + n * 16 + rsel0) * BK + kc * 8];
    #pragma unroll
    for (int m = 0; m < 4; ++m)
      #pragma unroll
      for (int n = 0; n < 4; ++n)
        acc[m][n] = __builtin_amdgcn_mfma_f32_16x16x32_bf16(af[m], bfr[n], acc[m][n], 0, 0, 0);

    __syncthreads();
  }

  // epilogue. C/D map: col = lane&15, row = (lane>>4)*4 + i
  const int rsel = lane & 15, quad = lane >> 4;
  float bvv[4];
  #pragma unroll
  for (int n = 0; n < 4; ++n)
    bvv[n] = ADD_BIAS ? bias[(size_t)e * BIAS_STRIDE + bn + wn * 64 + n * 16 + rsel] : 0.f;

  if constexpr (DOGELU) {
    #pragma unroll
    for (int m = 0; m < 4; ++m) {
      int r0 = row0 + wm * 64 + m * 16 + quad * 4;
      #pragma unroll
      for (int n = 0; n < 4; ++n) {
        int col = bn + wn * 64 + n * 16 + rsel;
        unsigned short* hp = Hout + (size_t)r0 * NDIM + col;
        #pragma unroll
        for (int i = 0; i < 4; ++i) {
          float v = acc[m][n][i] + bvv[n];
          hp[(size_t)i * NDIM] = f2bf(gelu_f(v));
        }
      }
    }
  } else {
    #pragma unroll
    for (int m = 0; m < 4; ++m) {
      #pragma unroll
      for (int i = 0; i < 4; ++i) {
        int p = row0 + wm * 64 + m * 16 + quad * 4 + i;
        int t = pair_tok[p];
        if (t < 0) continue;                    // padding row
        float w = pair_w[p];
        float* op = out + (size_t)t * HID;
        #pragma unroll
        for (int n = 0; n < 4; ++n) {
          int col = bn + wn * 64 + n * 16 + rsel;
          atomicAdd(op + col, w * (acc[m][n][i] + bvv[n]));
        }
      }
    }
  }
}

// ---------------- launch ----------------
extern "C" void kernel_launch(void* const* d_in, const int* in_sizes, int n_in,
                              void* d_out, int out_size, void* d_ws, size_t ws_size,
                              hipStream_t stream)
{
  const float* x  = (const float*)d_in[0];
  const float* Wr = (const float*)d_in[1];
  const float* W1 = (const float*)d_in[2];
  const float* b1 = (const float*)d_in[3];
  const float* W2 = (const float*)d_in[4];
  const float* b2 = (const float*)d_in[5];

  float* out        = (float*)d_out;                 // 4096*1024
  float* out_logits = out + (size_t)NTOK * HID;      // 4096*8
  float* out_sel    = out_logits + (size_t)NTOK * NE;// 4096*2 (as floats)

  char* ws = (char*)d_ws;
  int*   counts   = (int*)(ws + 0);        // 8
  int*   cursors  = (int*)(ws + 64);       // 8
  int*   nrb      = (int*)(ws + 128);      // 1
  int*   offs     = (int*)(ws + 192);      // 8
  int*   rb2e     = (int*)(ws + 256);      // 128
  int*   rb2row   = (int*)(ws + 768);      // 128
  int*   tok_sel  = (int*)(ws + 1280);     // 4096*2
  float* tok_w    = (float*)(ws + 34048);  // 4096*2
  int*   pair_tok = (int*)(ws + 66816);    // 9216
  float* pair_w   = (float*)(ws + 103680); // 9216
  unsigned short* Xg  = (unsigned short*)(ws + 140800);    // ROWCAP*1024 bf16 (18.9 MB)
  unsigned short* Hh  = (unsigned short*)(ws + 19015168);  // ROWCAP*2048 bf16 (37.7 MB)
  unsigned short* Wth = (unsigned short*)(ws + 56763904);  // 8*2048*1024 bf16 (33.5 MB, reused)
  // peak ws usage: 56763904 + 33554432 = 90,318,336 B = 90.3 MB (< 94.5 MB proven in R1)

  hipMemsetAsync(ws, 0, 256, stream);                          // counts/cursors/nrb
  hipMemsetAsync(pair_tok, 0xFF, (size_t)ROWCAP * 4, stream);  // -1 = padding
  hipMemsetAsync(d_out, 0, (size_t)out_size * 4, stream);

  router_k<<<NTOK / 4, 256, 0, stream>>>(x, Wr, out_logits, out_sel, counts, tok_sel, tok_w);
  scan_k<<<1, 64, 0, stream>>>(counts, offs, rb2e, rb2row, nrb);
  build_k<<<NTOK / 256, 256, 0, stream>>>(tok_sel, tok_w, offs, cursors, pair_tok, pair_w);
  gather_k<<<ROWCAP / 4, 256, 0, stream>>>(x, pair_tok, Xg);

  for (int h = 0; h < 2; ++h) {
    // W1 half: fp32 [H][FF] cols [h*2048, h*2048+2048) -> bf16 [E][2048][1024]
    dim3 gt1((HID / 64) * (FFH / 64), NE);
    wtrans_k<HID, FFH><<<gt1, 256, 0, stream>>>(
        W1 + (size_t)h * FFH, Wth, FFD, (size_t)HID * FFD);
    // GEMM1 half: Hh = gelu(Xg @ W1h + b1h)
    dim3 g1(FFH / BN, RBCAP);
    gemm_k<HID, FFH, FFD, true, true><<<g1, 256, 0, stream>>>(
        Xg, Wth, b1 + (size_t)h * FFH, nrb, rb2e, rb2row, Hh, nullptr, nullptr, nullptr);
    // W2 half: fp32 rows [h*2048, +2048) of [FF][H] -> bf16 [E][1024][2048]
    dim3 gt2((FFH / 64) * (HID / 64), NE);
    wtrans_k<FFH, HID><<<gt2, 256, 0, stream>>>(
        W2 + (size_t)h * FFH * HID, Wth, HID, (size_t)FFD * HID);
    // GEMM2 half: out[tok] += w * (Hh @ W2h) (+ b2 on first pass only)
    dim3 g2(HID / BN, HID / BN == 8 ? RBCAP : RBCAP);
    if (h == 0)
      gemm_k<FFH, HID, HID, false, true><<<dim3(HID / BN, RBCAP), 256, 0, stream>>>(
          Hh, Wth, b2, nrb, rb2e, rb2row, nullptr, pair_tok, pair_w, out);
    else
      gemm_k<FFH, HID, HID, false, false><<<dim3(HID / BN, RBCAP), 256, 0, stream>>>(
          Hh, Wth, b2, nrb, rb2e, rb2row, nullptr, pair_tok, pair_w, out);
  }
}

// Round 6
// 662.230 us; speedup vs baseline: 1.1677x; 1.1592x over previous
//
#include <hip/hip_runtime.h>
#include <hip/hip_bf16.h>
#include <stdint.h>

#define HID 1024
#define FFD 4096
#define FFH 2048          // FF half
#define NE  8
#define NTOK 4096
#define BM 128
#define BN 128
#define BK 32
#define RBCAP 72
#define ROWCAP (RBCAP*BM)   // 9216

typedef __attribute__((ext_vector_type(8))) short short8;
typedef __attribute__((ext_vector_type(4))) float f32x4;

__device__ __forceinline__ unsigned short f2bf(float f){
  union { float f; unsigned u; } v; v.f = f;
  return (unsigned short)((v.u + 0x7FFFu + ((v.u >> 16) & 1u)) >> 16);  // RNE
}

__device__ __forceinline__ float gelu_f(float x){
  float u = 0.7978845608028654f * (x + 0.044715f * x * x * x);
  return 0.5f * x * (1.0f + tanhf(u));
}

__device__ __forceinline__ void gload_lds16(const void* g, void* l){
  __builtin_amdgcn_global_load_lds((const __attribute__((address_space(1))) void*)g,
                                   (__attribute__((address_space(3))) void*)l,
                                   16, 0, 0);
}

// ---------------- router: logits (f64 accum), softmax fp32, top-2. NO atomics. ------------
__global__ __launch_bounds__(256) void router_k(
    const float* __restrict__ x, const float* __restrict__ Wr,
    float* __restrict__ out_logits, float* __restrict__ out_sel,
    int* __restrict__ tok_sel, float* __restrict__ tok_w)
{
  const int lane = threadIdx.x & 63;
  const int t = (blockIdx.x << 2) + (threadIdx.x >> 6);
  const float* xr = x + (size_t)t * HID;
  double acc[NE];
  #pragma unroll
  for (int e = 0; e < NE; ++e) acc[e] = 0.0;
  #pragma unroll
  for (int i = 0; i < 4; ++i) {
    const int h0 = i * 256 + lane * 4;
    float4 xv = *(const float4*)(xr + h0);
    #pragma unroll
    for (int r = 0; r < 4; ++r) {
      float xs = (&xv.x)[r];
      float4 w0 = *(const float4*)(Wr + (size_t)(h0 + r) * NE);
      float4 w1 = *(const float4*)(Wr + (size_t)(h0 + r) * NE + 4);
      acc[0] += (double)xs * w0.x;  acc[1] += (double)xs * w0.y;
      acc[2] += (double)xs * w0.z;  acc[3] += (double)xs * w0.w;
      acc[4] += (double)xs * w1.x;  acc[5] += (double)xs * w1.y;
      acc[6] += (double)xs * w1.z;  acc[7] += (double)xs * w1.w;
    }
  }
  #pragma unroll
  for (int off = 32; off > 0; off >>= 1) {
    #pragma unroll
    for (int e = 0; e < NE; ++e) acc[e] += __shfl_down(acc[e], off);
  }
  if (lane == 0) {
    float lg[NE], p[NE];
    float mx = -3.4e38f;
    #pragma unroll
    for (int e = 0; e < NE; ++e) { lg[e] = (float)acc[e]; mx = fmaxf(mx, lg[e]); }
    float s = 0.f;
    #pragma unroll
    for (int e = 0; e < NE; ++e) { p[e] = expf(lg[e] - mx); s += p[e]; }
    float inv = 1.0f / s;
    #pragma unroll
    for (int e = 0; e < NE; ++e) p[e] *= inv;
    #pragma unroll
    for (int e = 0; e < NE; ++e) out_logits[(size_t)t * NE + e] = lg[e];
    int e0 = 0;
    #pragma unroll
    for (int e = 1; e < NE; ++e) if (p[e] > p[e0]) e0 = e;      // tie -> lower idx
    int e1 = (e0 == 0) ? 1 : 0;
    #pragma unroll
    for (int e = 0; e < NE; ++e) if (e != e0 && p[e] > p[e1]) e1 = e;
    out_sel[(size_t)t * 2 + 0] = (float)e0;
    out_sel[(size_t)t * 2 + 1] = (float)e1;
    tok_sel[t * 2 + 0] = e0;  tok_sel[t * 2 + 1] = e1;
    tok_w[t * 2 + 0] = p[e0]; tok_w[t * 2 + 1] = p[e1];
  }
}

// ------- partition: histogram + scan + rowblock table + pair scatter, one block, no atomics
__global__ __launch_bounds__(1024) void part_k(
    const int* __restrict__ tok_sel, const float* __restrict__ tok_w,
    int* __restrict__ pair_tok, float* __restrict__ pair_w,
    int* __restrict__ rb2e, int* __restrict__ rb2row, int* __restrict__ nrb)
{
  __shared__ unsigned sc[1024][NE];
  __shared__ unsigned shOffs[NE];
  const int tid = threadIdx.x;
  int pe[8];
  unsigned cnt[NE] = {0,0,0,0,0,0,0,0};
  #pragma unroll
  for (int j = 0; j < 8; ++j) {
    int e = tok_sel[tid * 8 + j];
    pe[j] = e;
    #pragma unroll
    for (int k = 0; k < NE; ++k) cnt[k] += (e == k) ? 1u : 0u;   // static indexing
  }
  #pragma unroll
  for (int k = 0; k < NE; ++k) sc[tid][k] = cnt[k];
  __syncthreads();
  // inclusive scan across 1024 threads (vector element = 8 x u32)
  for (int off = 1; off < 1024; off <<= 1) {
    unsigned v[NE];
    const bool act = (tid >= off);
    if (act) {
      #pragma unroll
      for (int k = 0; k < NE; ++k) v[k] = sc[tid - off][k];
    }
    __syncthreads();
    if (act) {
      #pragma unroll
      for (int k = 0; k < NE; ++k) sc[tid][k] += v[k];
    }
    __syncthreads();
  }
  if (tid == 0) {
    unsigned row = 0; int rb = 0;
    #pragma unroll
    for (int e = 0; e < NE; ++e) {
      shOffs[e] = row;
      int nb = (int)((sc[1023][e] + 127u) >> 7);
      for (int b = 0; b < nb; ++b) { rb2e[rb] = e; rb2row[rb] = (int)row + b * BM; ++rb; }
      row += (unsigned)nb << 7;
    }
    nrb[0] = rb;
  }
  __syncthreads();
  // deterministic scatter (pair order = q order within each expert)
  #pragma unroll
  for (int j = 0; j < 8; ++j) {
    int e = pe[j];
    int rank = 0;
    #pragma unroll
    for (int j2 = 0; j2 < 8; ++j2) if (j2 < j) rank += (pe[j2] == e) ? 1 : 0;
    unsigned prev = (tid > 0) ? sc[tid - 1][e] : 0u;   // dynamic e -> LDS read, fine
    int p = (int)(shOffs[e] + prev) + rank;
    int q = tid * 8 + j;
    pair_tok[p] = q >> 1;
    pair_w[p] = tok_w[q];
  }
}

// ---------------- gather selected rows of x -> bf16 ----------------
__global__ __launch_bounds__(256) void gather_k(
    const float* __restrict__ x, const int* __restrict__ pair_tok, unsigned short* __restrict__ Xg)
{
  const int lane = threadIdx.x & 63;
  const int p = (blockIdx.x << 2) + (threadIdx.x >> 6);
  int t = pair_tok[p];
  if (t < 0) return;                       // padding row: never consumed
  const float* src = x + (size_t)t * HID;
  unsigned short* dst = Xg + (size_t)p * HID;
  #pragma unroll
  for (int i = 0; i < 4; ++i) {
    float4 v = *(const float4*)(src + lane * 4 + i * 256);
    unsigned a = (unsigned)f2bf(v.x) | ((unsigned)f2bf(v.y) << 16);
    unsigned b = (unsigned)f2bf(v.z) | ((unsigned)f2bf(v.w) << 16);
    *(uint2*)(dst + lane * 4 + i * 256) = make_uint2(a, b);
  }
}

// ------- generic weight transpose+convert: out[e][n][k] = bf16(in_e[k*ld_in + n]) -------
template<int KSUB, int NSUB>
__global__ __launch_bounds__(256) void wtrans_k(const float* __restrict__ in,
                                               unsigned short* __restrict__ out,
                                               int ld_in, size_t in_estride)
{
  const int tilesN = NSUB / 64;
  const int tk = blockIdx.x / tilesN, tn = blockIdx.x % tilesN;
  const int k0 = tk * 64, n0 = tn * 64;
  const float* ine = in + (size_t)blockIdx.y * in_estride;
  unsigned short* oute = out + (size_t)blockIdx.y * KSUB * NSUB;
  __shared__ unsigned short lds[64][65];   // [n][k]
  const int t = threadIdx.x;
  #pragma unroll
  for (int i = 0; i < 4; ++i) {
    int f = i * 256 + t;
    int krow = f >> 4, c4 = (f & 15) * 4;
    float4 v = *(const float4*)(ine + (size_t)(k0 + krow) * ld_in + n0 + c4);
    lds[c4 + 0][krow] = f2bf(v.x);
    lds[c4 + 1][krow] = f2bf(v.y);
    lds[c4 + 2][krow] = f2bf(v.z);
    lds[c4 + 3][krow] = f2bf(v.w);
  }
  __syncthreads();
  #pragma unroll
  for (int i = 0; i < 4; ++i) {
    int g = i * 256 + t;
    int nrow = g >> 4, kc = (g & 15) * 4;
    unsigned short a0 = lds[nrow][kc], a1 = lds[nrow][kc + 1];
    unsigned short a2 = lds[nrow][kc + 2], a3 = lds[nrow][kc + 3];
    uint2 w;
    w.x = (unsigned)a0 | ((unsigned)a1 << 16);
    w.y = (unsigned)a2 | ((unsigned)a3 << 16);
    *(uint2*)(oute + (size_t)(n0 + nrow) * KSUB + k0 + kc) = w;
  }
}

// ---------------- expert-tiled GEMM (m97 structure: both operands via global_load_lds) ----
template<int KDIM, int NDIM, int BIAS_STRIDE, bool DOGELU, bool ADD_BIAS>
__global__ __launch_bounds__(256) void gemm_k(
    const unsigned short* __restrict__ A, const unsigned short* __restrict__ Bt,
    const float* __restrict__ bias,
    const int* __restrict__ nrb, const int* __restrict__ rb2e, const int* __restrict__ rb2row,
    unsigned short* __restrict__ Hout,
    const int* __restrict__ pair_tok, const float* __restrict__ pair_w,
    float* __restrict__ out)
{
  if ((int)blockIdx.y >= nrb[0]) return;
  const int e    = rb2e[blockIdx.y];
  const int row0 = rb2row[blockIdx.y];
  const int bn   = blockIdx.x * BN;

  __shared__ __align__(16) unsigned short As[BM * BK];   // [row][k]
  __shared__ __align__(16) unsigned short Bs[BN * BK];   // [n][k]

  const int tid = threadIdx.x;
  const int lane = tid & 63, wave = tid >> 6;
  const int wm = wave >> 1, wn = wave & 1;
  const unsigned short* Be = Bt + (size_t)e * KDIM * NDIM;

  f32x4 acc[4][4];
  #pragma unroll
  for (int m = 0; m < 4; ++m)
    #pragma unroll
    for (int n = 0; n < 4; ++n) acc[m][n] = f32x4{0.f, 0.f, 0.f, 0.f};

  for (int kt = 0; kt < KDIM; kt += BK) {
    #pragma unroll
    for (int r = 0; r < 2; ++r) {
      int c = r * 256 + tid;
      int mrow = c >> 2;               // 4 chunks (=32 bf16) per row
      int koff = (c & 3) * 8;
      const void* gpa = (const void*)(A + (size_t)(row0 + mrow) * KDIM + kt + koff);
      void* lpa = (void*)(As + (size_t)(r * 256 + wave * 64) * 8);
      gload_lds16(gpa, lpa);
      const void* gpb = (const void*)(Be + (size_t)(bn + mrow) * KDIM + kt + koff);
      void* lpb = (void*)(Bs + (size_t)(r * 256 + wave * 64) * 8);
      gload_lds16(gpb, lpb);
    }
    __syncthreads();

    const int kc = lane >> 4, rsel0 = lane & 15;
    short8 af[4], bfr[4];
    #pragma unroll
    for (int m = 0; m < 4; ++m)
      af[m] = *(const short8*)&As[(wm * 64 + m * 16 + rsel0) * BK + kc * 8];
    #pragma unroll
    for (int n = 0; n < 4; ++n)
      bfr[n] = *(const short8*)&Bs[(wn * 64 + n * 16 + rsel0) * BK + kc * 8];
    #pragma unroll
    for (int m = 0; m < 4; ++m)
      #pragma unroll
      for (int n = 0; n < 4; ++n)
        acc[m][n] = __builtin_amdgcn_mfma_f32_16x16x32_bf16(af[m], bfr[n], acc[m][n], 0, 0, 0);

    __syncthreads();
  }

  // epilogue. C/D map: col = lane&15, row = (lane>>4)*4 + i
  const int rsel = lane & 15, quad = lane >> 4;
  float bvv[4];
  #pragma unroll
  for (int n = 0; n < 4; ++n)
    bvv[n] = ADD_BIAS ? bias[(size_t)e * BIAS_STRIDE + bn + wn * 64 + n * 16 + rsel] : 0.f;

  if constexpr (DOGELU) {
    #pragma unroll
    for (int m = 0; m < 4; ++m) {
      int r0 = row0 + wm * 64 + m * 16 + quad * 4;
      #pragma unroll
      for (int n = 0; n < 4; ++n) {
        int col = bn + wn * 64 + n * 16 + rsel;
        unsigned short* hp = Hout + (size_t)r0 * NDIM + col;
        #pragma unroll
        for (int i = 0; i < 4; ++i) {
          float v = acc[m][n][i] + bvv[n];
          hp[(size_t)i * NDIM] = f2bf(gelu_f(v));
        }
      }
    }
  } else {
    #pragma unroll
    for (int m = 0; m < 4; ++m) {
      #pragma unroll
      for (int i = 0; i < 4; ++i) {
        int p = row0 + wm * 64 + m * 16 + quad * 4 + i;
        int t = pair_tok[p];
        if (t < 0) continue;                    // padding row
        float w = pair_w[p];
        float* op = out + (size_t)t * HID;
        #pragma unroll
        for (int n = 0; n < 4; ++n) {
          int col = bn + wn * 64 + n * 16 + rsel;
          atomicAdd(op + col, w * (acc[m][n][i] + bvv[n]));
        }
      }
    }
  }
}

// ---------------- launch ----------------
extern "C" void kernel_launch(void* const* d_in, const int* in_sizes, int n_in,
                              void* d_out, int out_size, void* d_ws, size_t ws_size,
                              hipStream_t stream)
{
  const float* x  = (const float*)d_in[0];
  const float* Wr = (const float*)d_in[1];
  const float* W1 = (const float*)d_in[2];
  const float* b1 = (const float*)d_in[3];
  const float* W2 = (const float*)d_in[4];
  const float* b2 = (const float*)d_in[5];

  float* out        = (float*)d_out;                 // 4096*1024
  float* out_logits = out + (size_t)NTOK * HID;      // 4096*8
  float* out_sel    = out_logits + (size_t)NTOK * NE;// 4096*2 (as floats)

  char* ws = (char*)d_ws;
  int*   nrb      = (int*)(ws + 128);      // 1
  int*   rb2e     = (int*)(ws + 256);      // 128
  int*   rb2row   = (int*)(ws + 768);      // 128
  int*   tok_sel  = (int*)(ws + 1280);     // 4096*2
  float* tok_w    = (float*)(ws + 34048);  // 4096*2
  int*   pair_tok = (int*)(ws + 66816);    // 9216
  float* pair_w   = (float*)(ws + 103680); // 9216
  unsigned short* Xg  = (unsigned short*)(ws + 140800);    // ROWCAP*1024 bf16 (18.9 MB)
  unsigned short* Hh  = (unsigned short*)(ws + 19015168);  // ROWCAP*2048 bf16 (37.7 MB)
  unsigned short* Wth = (unsigned short*)(ws + 56763904);  // 8*2048*1024 bf16 (33.5 MB, reused)
  // peak ws usage: 56763904 + 33554432 = 90,318,336 B = 90.3 MB (< 94.5 MB proven in R1)

  hipMemsetAsync(pair_tok, 0xFF, (size_t)ROWCAP * 4, stream);  // -1 = padding
  hipMemsetAsync(d_out, 0, (size_t)out_size * 4, stream);

  router_k<<<NTOK / 4, 256, 0, stream>>>(x, Wr, out_logits, out_sel, tok_sel, tok_w);
  part_k<<<1, 1024, 0, stream>>>(tok_sel, tok_w, pair_tok, pair_w, rb2e, rb2row, nrb);
  gather_k<<<ROWCAP / 4, 256, 0, stream>>>(x, pair_tok, Xg);

  for (int h = 0; h < 2; ++h) {
    // W1 half: fp32 [H][FF] cols [h*2048, h*2048+2048) -> bf16 [E][2048][1024]
    dim3 gt1((HID / 64) * (FFH / 64), NE);
    wtrans_k<HID, FFH><<<gt1, 256, 0, stream>>>(
        W1 + (size_t)h * FFH, Wth, FFD, (size_t)HID * FFD);
    // GEMM1 half: Hh = gelu(Xg @ W1h + b1h)
    dim3 g1(FFH / BN, RBCAP);
    gemm_k<HID, FFH, FFD, true, true><<<g1, 256, 0, stream>>>(
        Xg, Wth, b1 + (size_t)h * FFH, nrb, rb2e, rb2row, Hh, nullptr, nullptr, nullptr);
    // W2 half: fp32 rows [h*2048, +2048) of [FF][H] -> bf16 [E][1024][2048]
    dim3 gt2((FFH / 64) * (HID / 64), NE);
    wtrans_k<FFH, HID><<<gt2, 256, 0, stream>>>(
        W2 + (size_t)h * FFH * HID, Wth, HID, (size_t)FFD * HID);
    // GEMM2 half: out[tok] += w * (Hh @ W2h) (+ b2 on first pass only)
    if (h == 0)
      gemm_k<FFH, HID, HID, false, true><<<dim3(HID / BN, RBCAP), 256, 0, stream>>>(
          Hh, Wth, b2, nrb, rb2e, rb2row, nullptr, pair_tok, pair_w, out);
    else
      gemm_k<FFH, HID, HID, false, false><<<dim3(HID / BN, RBCAP), 256, 0, stream>>>(
          Hh, Wth, b2, nrb, rb2e, rb2row, nullptr, pair_tok, pair_w, out);
  }
}